// Round 2
// baseline (4165.817 us; speedup 1.0000x reference)
//
#include <hip/hip_runtime.h>
#include <math.h>

#define NN 100000      // nodes
#define DIN 128        // input features
#define NC 10          // classes
#define PAD 16         // padded row stride (floats) for node arrays -> 64B rows
#define MU 800000      // undirected edge pairs
#define EE (2 * MU)    // directed edges

// ---------------------------------------------------------------------------
// Kernel 1: log_b0 = log_softmax(x @ W + b); init log_b = log_b0; zero agg.
// W (128x10) + b staged in LDS; all LDS reads are wave-uniform broadcasts.
// ---------------------------------------------------------------------------
__global__ __launch_bounds__(256) void transform_kernel(
    const float* __restrict__ x, const float* __restrict__ W,
    const float* __restrict__ b, float* __restrict__ log_b0,
    float* __restrict__ log_b, float* __restrict__ agg)
{
    __shared__ float Ws[DIN * NC];
    __shared__ float bs[NC];
    for (int i = threadIdx.x; i < DIN * NC; i += 256) Ws[i] = W[i];
    if (threadIdx.x < NC) bs[threadIdx.x] = b[threadIdx.x];
    __syncthreads();

    int n = blockIdx.x * 256 + threadIdx.x;
    if (n >= NN) return;

    float acc[NC];
#pragma unroll
    for (int c = 0; c < NC; ++c) acc[c] = bs[c];

    const float4* xr = reinterpret_cast<const float4*>(x + (size_t)n * DIN);
#pragma unroll 4
    for (int k4 = 0; k4 < DIN / 4; ++k4) {
        float4 xv = xr[k4];
#pragma unroll
        for (int c = 0; c < NC; ++c) {
            acc[c] = fmaf(xv.x, Ws[(k4 * 4 + 0) * NC + c], acc[c]);
            acc[c] = fmaf(xv.y, Ws[(k4 * 4 + 1) * NC + c], acc[c]);
            acc[c] = fmaf(xv.z, Ws[(k4 * 4 + 2) * NC + c], acc[c]);
            acc[c] = fmaf(xv.w, Ws[(k4 * 4 + 3) * NC + c], acc[c]);
        }
    }
    float m = acc[0];
#pragma unroll
    for (int c = 1; c < NC; ++c) m = fmaxf(m, acc[c]);
    float s = 0.f;
#pragma unroll
    for (int c = 0; c < NC; ++c) s += __expf(acc[c] - m);
    float lse = m + __logf(s);

    size_t o = (size_t)n * PAD;
#pragma unroll
    for (int c = 0; c < NC; ++c) {
        float v = acc[c] - lse;
        log_b0[o + c] = v;
        log_b [o + c] = v;
        agg   [o + c] = 0.f;
    }
}

// ---------------------------------------------------------------------------
// Kernel 2: edge update, one thread per UNDIRECTED pair (e, e+MU).
// rv structure (rv[e]=e+MU) lets the same thread own both directions ->
// in-place message update, no double buffering.
//
// Message math: v1 = log_b[src] - old_reverse_msg; out = log(p@H) - log(sum)
// with p = exp(v1 - max(v1)); the max and the -log(C) uniform init cancel.
//
// log_msg is SoA: plane c at log_msg[c*EE + e]  (fully coalesced r/w).
// New messages atomicAdd into agg (padded rows).
// ---------------------------------------------------------------------------
template <int FIRST>
__global__ __launch_bounds__(256) void edge_kernel(
    const int* __restrict__ ei,      // [2, EE]
    const float* __restrict__ T,     // [NC, NC]
    const float* __restrict__ log_b, // [NN, PAD]
    float* __restrict__ log_msg,     // [NC, EE] planes
    float* __restrict__ agg)         // [NN, PAD]
{
    __shared__ float Hs[NC * NC];
    if (threadIdx.x < NC * NC) {
        int i = threadIdx.x / NC, j = threadIdx.x % NC;
        float d2 = 0.f;
#pragma unroll
        for (int k = 0; k < NC; ++k) {
            float d = T[i * NC + k] - T[j * NC + k];
            d2 = fmaf(d, d, d2);
        }
        Hs[threadIdx.x] = __expf(-d2);
    }
    __syncthreads();

    int e = blockIdx.x * 256 + threadIdx.x;
    if (e >= MU) return;

    int u = ei[e];          // directed edge e:    u -> v
    int v = ei[MU * 2 + e]; // directed edge e+MU: v -> u

    // v1 for each direction (iter 0: uniform old msg == constant -> cancels)
    float v_uv[NC], v_vu[NC];
    {
        const float* pu = log_b + (size_t)u * PAD;
        const float* pv = log_b + (size_t)v * PAD;
        if (FIRST) {
#pragma unroll
            for (int c = 0; c < NC; ++c) { v_uv[c] = pu[c]; v_vu[c] = pv[c]; }
        } else {
#pragma unroll
            for (int c = 0; c < NC; ++c) {
                float mo_uv = log_msg[(size_t)c * EE + e];       // old u->v
                float mo_vu = log_msg[(size_t)c * EE + MU + e];  // old v->u
                v_uv[c] = pu[c] - mo_vu;   // u->v subtracts reverse (v->u)
                v_vu[c] = pv[c] - mo_uv;
            }
        }
    }

    float m_uv = v_uv[0], m_vu = v_vu[0];
#pragma unroll
    for (int c = 1; c < NC; ++c) {
        m_uv = fmaxf(m_uv, v_uv[c]);
        m_vu = fmaxf(m_vu, v_vu[c]);
    }
    float p_uv[NC], p_vu[NC];
#pragma unroll
    for (int c = 0; c < NC; ++c) {
        p_uv[c] = __expf(v_uv[c] - m_uv);
        p_vu[c] = __expf(v_vu[c] - m_vu);
    }

    float q_uv[NC], q_vu[NC];
#pragma unroll
    for (int c = 0; c < NC; ++c) { q_uv[c] = 0.f; q_vu[c] = 0.f; }
#pragma unroll
    for (int c1 = 0; c1 < NC; ++c1) {
        float a = p_uv[c1], bb = p_vu[c1];
#pragma unroll
        for (int c2 = 0; c2 < NC; ++c2) {
            float h = Hs[c1 * NC + c2];      // shared by both directions (CSE)
            q_uv[c2] = fmaf(a, h, q_uv[c2]);
            q_vu[c2] = fmaf(bb, h, q_vu[c2]);
        }
    }
    float Q_uv = 0.f, Q_vu = 0.f;
#pragma unroll
    for (int c = 0; c < NC; ++c) { Q_uv += q_uv[c]; Q_vu += q_vu[c]; }
    float lQ_uv = __logf(Q_uv), lQ_vu = __logf(Q_vu);

    float* av = agg + (size_t)v * PAD;
    float* au = agg + (size_t)u * PAD;
#pragma unroll
    for (int c = 0; c < NC; ++c) {
        float nm_uv = __logf(q_uv[c]) - lQ_uv;
        float nm_vu = __logf(q_vu[c]) - lQ_vu;
        log_msg[(size_t)c * EE + e]      = nm_uv;
        log_msg[(size_t)c * EE + MU + e] = nm_vu;
        atomicAdd(av + c, nm_uv);
        atomicAdd(au + c, nm_vu);
    }
}

// ---------------------------------------------------------------------------
// Kernel 3: log_b = log_normalize(agg + log_b0); reset agg to 0.
// LAST iteration writes the unpadded d_out instead of log_b.
// ---------------------------------------------------------------------------
template <int LAST>
__global__ __launch_bounds__(256) void node_kernel(
    const float* __restrict__ log_b0, float* __restrict__ agg,
    float* __restrict__ log_b, float* __restrict__ out)
{
    int n = blockIdx.x * 256 + threadIdx.x;
    if (n >= NN) return;
    size_t o = (size_t)n * PAD;
    float a[NC];
#pragma unroll
    for (int c = 0; c < NC; ++c) {
        a[c] = agg[o + c] + log_b0[o + c];
        agg[o + c] = 0.f;
    }
    float m = a[0];
#pragma unroll
    for (int c = 1; c < NC; ++c) m = fmaxf(m, a[c]);
    float s = 0.f;
#pragma unroll
    for (int c = 0; c < NC; ++c) s += __expf(a[c] - m);
    float lse = m + __logf(s);
    if (LAST) {
#pragma unroll
        for (int c = 0; c < NC; ++c) out[(size_t)n * NC + c] = a[c] - lse;
    } else {
#pragma unroll
        for (int c = 0; c < NC; ++c) log_b[o + c] = a[c] - lse;
    }
}

// ---------------------------------------------------------------------------
extern "C" void kernel_launch(void* const* d_in, const int* in_sizes, int n_in,
                              void* d_out, int out_size, void* d_ws, size_t ws_size,
                              hipStream_t stream)
{
    const float* x  = (const float*)d_in[0];
    const int*   ei = (const int*)d_in[1];
    // d_in[2] = rv — structure known (e <-> e+MU), not needed.
    const float* W  = (const float*)d_in[3];
    const float* b  = (const float*)d_in[4];
    const float* T  = (const float*)d_in[5];
    float* out = (float*)d_out;

    float* ws      = (float*)d_ws;
    float* log_b0  = ws;                        // NN*PAD
    float* log_b   = log_b0 + (size_t)NN * PAD; // NN*PAD
    float* agg     = log_b  + (size_t)NN * PAD; // NN*PAD
    float* log_msg = agg    + (size_t)NN * PAD; // NC*EE (SoA planes)

    const int nodeBlocks = (NN + 255) / 256;    // 391
    const int edgeBlocks = (MU + 255) / 256;    // 3125

    transform_kernel<<<nodeBlocks, 256, 0, stream>>>(x, W, b, log_b0, log_b, agg);

    // iteration 0: uniform old messages (constant cancels -> no msg read)
    edge_kernel<1><<<edgeBlocks, 256, 0, stream>>>(ei, T, log_b, log_msg, agg);
    node_kernel<0><<<nodeBlocks, 256, 0, stream>>>(log_b0, agg, log_b, out);

    // iterations 1..4
    for (int it = 1; it < 5; ++it) {
        edge_kernel<0><<<edgeBlocks, 256, 0, stream>>>(ei, T, log_b, log_msg, agg);
        if (it < 4)
            node_kernel<0><<<nodeBlocks, 256, 0, stream>>>(log_b0, agg, log_b, out);
        else
            node_kernel<1><<<nodeBlocks, 256, 0, stream>>>(log_b0, agg, log_b, out);
    }
}

// Round 5
// 730.568 us; speedup vs baseline: 5.7022x; 5.7022x over previous
//
#include <hip/hip_runtime.h>
#include <math.h>

#define NN 100000      // nodes
#define DIN 128        // input features
#define NC 10          // classes
#define PAD 16         // node-array row stride (floats) -> 64B rows (1 cache line)
#define MPAD 10        // msg row stride (floats) -> 40B rows (8B aligned)
#define MU 800000      // undirected edge pairs
#define EE (2 * MU)    // directed edges

// ---------- load/store 10 floats, 16B-aligned row (node arrays) ------------
__device__ __forceinline__ void load_row16(const float* __restrict__ p, float* r) {
    float4 v0 = *reinterpret_cast<const float4*>(p);
    float4 v1 = *reinterpret_cast<const float4*>(p + 4);
    float2 v2 = *reinterpret_cast<const float2*>(p + 8);
    r[0]=v0.x; r[1]=v0.y; r[2]=v0.z; r[3]=v0.w;
    r[4]=v1.x; r[5]=v1.y; r[6]=v1.z; r[7]=v1.w;
    r[8]=v2.x; r[9]=v2.y;
}
// ---------- load/store 10 floats, 8B-aligned row (msg array) ---------------
__device__ __forceinline__ void load_row8(const float* __restrict__ p, float* r) {
#pragma unroll
    for (int i = 0; i < 5; ++i) {
        float2 v = *reinterpret_cast<const float2*>(p + 2 * i);
        r[2 * i] = v.x; r[2 * i + 1] = v.y;
    }
}
__device__ __forceinline__ void store_row8(float* __restrict__ p, const float* r) {
#pragma unroll
    for (int i = 0; i < 5; ++i)
        *reinterpret_cast<float2*>(p + 2 * i) = make_float2(r[2 * i], r[2 * i + 1]);
}

// ---------------------------------------------------------------------------
// K0: log_b0 = log_softmax(x @ W + b); log_b = log_b0; deg[n] = 0.
// ---------------------------------------------------------------------------
__global__ __launch_bounds__(256) void transform_kernel(
    const float* __restrict__ x, const float* __restrict__ W,
    const float* __restrict__ b, float* __restrict__ log_b0,
    float* __restrict__ log_b, int* __restrict__ deg)
{
    __shared__ float Ws[DIN * NC];
    __shared__ float bs[NC];
    for (int i = threadIdx.x; i < DIN * NC; i += 256) Ws[i] = W[i];
    if (threadIdx.x < NC) bs[threadIdx.x] = b[threadIdx.x];
    __syncthreads();

    int n = blockIdx.x * 256 + threadIdx.x;
    if (n >= NN) return;

    float acc[NC];
#pragma unroll
    for (int c = 0; c < NC; ++c) acc[c] = bs[c];

    const float4* xr = reinterpret_cast<const float4*>(x + (size_t)n * DIN);
#pragma unroll 4
    for (int k4 = 0; k4 < DIN / 4; ++k4) {
        float4 xv = xr[k4];
#pragma unroll
        for (int c = 0; c < NC; ++c) {
            acc[c] = fmaf(xv.x, Ws[(k4 * 4 + 0) * NC + c], acc[c]);
            acc[c] = fmaf(xv.y, Ws[(k4 * 4 + 1) * NC + c], acc[c]);
            acc[c] = fmaf(xv.z, Ws[(k4 * 4 + 2) * NC + c], acc[c]);
            acc[c] = fmaf(xv.w, Ws[(k4 * 4 + 3) * NC + c], acc[c]);
        }
    }
    float m = acc[0];
#pragma unroll
    for (int c = 1; c < NC; ++c) m = fmaxf(m, acc[c]);
    float s = 0.f;
#pragma unroll
    for (int c = 0; c < NC; ++c) s += __expf(acc[c] - m);
    float lse = m + __logf(s);

    size_t o = (size_t)n * PAD;
#pragma unroll
    for (int c = 0; c < NC; ++c) {
        float v = acc[c] - lse;
        log_b0[o + c] = v;
        log_b [o + c] = v;
    }
    deg[n] = 0;
}

// ---------------------------------------------------------------------------
// CSR build (once per launch): count -> scan -> fill   (eid[slot] = edge id)
// ---------------------------------------------------------------------------
__global__ __launch_bounds__(256) void count_kernel(
    const int* __restrict__ ei, int* __restrict__ deg)
{
    int e = blockIdx.x * 256 + threadIdx.x;
    if (e >= EE) return;
    atomicAdd(&deg[ei[EE + e]], 1);   // dst of directed edge e
}

__global__ __launch_bounds__(256) void scan1_kernel(
    const int* __restrict__ deg, int* __restrict__ row, int* __restrict__ bsum)
{
    __shared__ int tmp[256];
    int t = threadIdx.x;
    int n = blockIdx.x * 256 + t;
    int val = (n < NN) ? deg[n] : 0;
    tmp[t] = val;
    __syncthreads();
#pragma unroll
    for (int off = 1; off < 256; off <<= 1) {
        int v = (t >= off) ? tmp[t - off] : 0;
        __syncthreads();
        tmp[t] += v;
        __syncthreads();
    }
    if (n < NN) row[n] = tmp[t] - val;      // exclusive within block
    if (t == 255) bsum[blockIdx.x] = tmp[t];
}

__global__ __launch_bounds__(512) void scan2_kernel(int* __restrict__ bsum, int nb)
{
    __shared__ int tmp[512];
    int t = threadIdx.x;
    tmp[t] = (t < nb) ? bsum[t] : 0;
    __syncthreads();
#pragma unroll
    for (int off = 1; off < 512; off <<= 1) {
        int v = (t >= off) ? tmp[t - off] : 0;
        __syncthreads();
        tmp[t] += v;
        __syncthreads();
    }
    if (t < nb) bsum[t] = (t == 0) ? 0 : tmp[t - 1];   // exclusive
}

// row[n] += bsum[block]; cursor[n] = row[n]; row[NN] = EE
__global__ __launch_bounds__(256) void scan3_kernel(
    int* __restrict__ row, const int* __restrict__ bsum, int* __restrict__ cursor)
{
    int n = blockIdx.x * 256 + threadIdx.x;
    if (n >= NN) return;
    int r = row[n] + bsum[blockIdx.x];
    row[n] = r;
    cursor[n] = r;
    if (n == 0) row[NN] = EE;
}

// eid[slot] = directed edge id, slots grouped by dst node
__global__ __launch_bounds__(256) void fill_kernel(
    const int* __restrict__ ei, int* __restrict__ cursor, int* __restrict__ eid)
{
    int e = blockIdx.x * 256 + threadIdx.x;
    if (e >= EE) return;
    eid[atomicAdd(&cursor[ei[EE + e]], 1)] = e;
}

// ---------------------------------------------------------------------------
// K1: edge update, one thread per UNDIRECTED pair (e, e+MU). msg is e-indexed:
// reads AND writes are contiguous streams, zero index loads, zero atomics.
// In-place is race-free: the pair thread owns both directions (rv[e]=e±MU).
//   v1 = log_b[src] - old_reverse_msg; out = log(p@H) - log(sum(p@H)),
//   p = exp(v1 - max); max and the uniform-init constant cancel.
// ---------------------------------------------------------------------------
template <int FIRST>
__global__ __launch_bounds__(256) void edge_kernel(
    const int* __restrict__ ei,       // [2, EE]
    const float* __restrict__ T,      // [NC, NC]
    const float* __restrict__ log_b,  // [NN, PAD]
    float* __restrict__ msg)          // [EE, MPAD] rows, e-indexed
{
    __shared__ float Hs[NC * NC];
    if (threadIdx.x < NC * NC) {
        int i = threadIdx.x / NC, j = threadIdx.x % NC;
        float d2 = 0.f;
#pragma unroll
        for (int k = 0; k < NC; ++k) {
            float d = T[i * NC + k] - T[j * NC + k];
            d2 = fmaf(d, d, d2);
        }
        Hs[threadIdx.x] = __expf(-d2);
    }
    __syncthreads();

    int e = blockIdx.x * 256 + threadIdx.x;
    if (e >= MU) return;

    int u = ei[e];          // directed edge e:    u -> v
    int v = ei[EE + e];     // directed edge e+MU: v -> u

    float* muv = msg + (size_t)e * MPAD;
    float* mvu = msg + (size_t)(e + MU) * MPAD;

    float lbu[NC], lbv[NC];
    load_row16(log_b + (size_t)u * PAD, lbu);
    load_row16(log_b + (size_t)v * PAD, lbv);

    float v_uv[NC], v_vu[NC];
    if (FIRST) {
#pragma unroll
        for (int c = 0; c < NC; ++c) { v_uv[c] = lbu[c]; v_vu[c] = lbv[c]; }
    } else {
        float mo_uv[NC], mo_vu[NC];
        load_row8(muv, mo_uv);
        load_row8(mvu, mo_vu);
#pragma unroll
        for (int c = 0; c < NC; ++c) {
            v_uv[c] = lbu[c] - mo_vu[c];   // u->v subtracts reverse (v->u)
            v_vu[c] = lbv[c] - mo_uv[c];
        }
    }

    float m_uv = v_uv[0], m_vu = v_vu[0];
#pragma unroll
    for (int c = 1; c < NC; ++c) {
        m_uv = fmaxf(m_uv, v_uv[c]);
        m_vu = fmaxf(m_vu, v_vu[c]);
    }
    float p_uv[NC], p_vu[NC];
#pragma unroll
    for (int c = 0; c < NC; ++c) {
        p_uv[c] = __expf(v_uv[c] - m_uv);
        p_vu[c] = __expf(v_vu[c] - m_vu);
    }
    float q_uv[NC], q_vu[NC];
#pragma unroll
    for (int c = 0; c < NC; ++c) { q_uv[c] = 0.f; q_vu[c] = 0.f; }
#pragma unroll
    for (int c1 = 0; c1 < NC; ++c1) {
        float a = p_uv[c1], bb = p_vu[c1];
#pragma unroll
        for (int c2 = 0; c2 < NC; ++c2) {
            float h = Hs[c1 * NC + c2];      // shared by both directions (CSE)
            q_uv[c2] = fmaf(a, h, q_uv[c2]);
            q_vu[c2] = fmaf(bb, h, q_vu[c2]);
        }
    }
    float Q_uv = 0.f, Q_vu = 0.f;
#pragma unroll
    for (int c = 0; c < NC; ++c) { Q_uv += q_uv[c]; Q_vu += q_vu[c]; }
    float lQ_uv = __logf(Q_uv), lQ_vu = __logf(Q_vu);

    float nm_uv[NC], nm_vu[NC];
#pragma unroll
    for (int c = 0; c < NC; ++c) {
        nm_uv[c] = __logf(q_uv[c]) - lQ_uv;
        nm_vu[c] = __logf(q_vu[c]) - lQ_vu;
    }
    store_row8(muv, nm_uv);
    store_row8(mvu, nm_vu);
}

// ---------------------------------------------------------------------------
// K2: per-node: gather incoming msg rows via eid, sum + log_b0, normalize.
// msg is L3-resident (64MB); gathers are 40B rows. Zero atomics.
// ---------------------------------------------------------------------------
template <int LAST>
__global__ __launch_bounds__(256) void node_kernel(
    const int* __restrict__ row, const int* __restrict__ eid,
    const float* __restrict__ msg, const float* __restrict__ log_b0,
    float* __restrict__ log_b, float* __restrict__ out)
{
    int n = blockIdx.x * 256 + threadIdx.x;
    if (n >= NN) return;

    float a[NC];
    load_row16(log_b0 + (size_t)n * PAD, a);

    int r0 = row[n], r1 = row[n + 1];
    for (int s = r0; s < r1; ++s) {
        int e = eid[s];
        float t[NC];
        load_row8(msg + (size_t)e * MPAD, t);
#pragma unroll
        for (int c = 0; c < NC; ++c) a[c] += t[c];
    }

    float m = a[0];
#pragma unroll
    for (int c = 1; c < NC; ++c) m = fmaxf(m, a[c]);
    float s = 0.f;
#pragma unroll
    for (int c = 0; c < NC; ++c) s += __expf(a[c] - m);
    float lse = m + __logf(s);

    if (LAST) {
#pragma unroll
        for (int c = 0; c < NC; ++c) out[(size_t)n * NC + c] = a[c] - lse;
    } else {
        size_t o = (size_t)n * PAD;
#pragma unroll
        for (int c = 0; c < NC; ++c) log_b[o + c] = a[c] - lse;
    }
}

// ---------------------------------------------------------------------------
extern "C" void kernel_launch(void* const* d_in, const int* in_sizes, int n_in,
                              void* d_out, int out_size, void* d_ws, size_t ws_size,
                              hipStream_t stream)
{
    const float* x  = (const float*)d_in[0];
    const int*   ei = (const int*)d_in[1];
    // d_in[2] = rv — structure known (rv[e] = e +/- MU), not needed.
    const float* W  = (const float*)d_in[3];
    const float* b  = (const float*)d_in[4];
    const float* T  = (const float*)d_in[5];
    float* out = (float*)d_out;

    // ---- workspace layout, total ~84 MB (matches round-2's proven footprint)
    float* ws      = (float*)d_ws;
    float* log_b0  = ws;                          // NN*PAD       6.4 MB
    float* log_b   = log_b0 + (size_t)NN * PAD;   // NN*PAD       6.4 MB
    float* msg     = log_b  + (size_t)NN * PAD;   // EE*MPAD     64.0 MB
    int*   eid     = (int*)(msg + (size_t)EE * MPAD); // EE       6.4 MB
    int*   deg     = eid + EE;                    // NN (doubles as cursor)
    int*   row     = deg + NN;                    // NN+16
    int*   bsum    = row + NN + 16;               // 512

    const int nodeBlocks = (NN + 255) / 256;   // 391
    const int pairBlocks = (MU + 255) / 256;   // 3125
    const int edgeBlocks = (EE + 255) / 256;   // 6250

    // transform + zero deg
    transform_kernel<<<nodeBlocks, 256, 0, stream>>>(x, W, b, log_b0, log_b, deg);

    // CSR-by-dst build — one-time; removes all per-iteration atomics
    count_kernel<<<edgeBlocks, 256, 0, stream>>>(ei, deg);
    scan1_kernel<<<nodeBlocks, 256, 0, stream>>>(deg, row, bsum);
    scan2_kernel<<<1, 512, 0, stream>>>(bsum, nodeBlocks);
    scan3_kernel<<<nodeBlocks, 256, 0, stream>>>(row, bsum, deg);  // deg -> cursor
    fill_kernel<<<edgeBlocks, 256, 0, stream>>>(ei, deg, eid);

    // iteration 0 (uniform old messages cancel -> no msg read)
    edge_kernel<1><<<pairBlocks, 256, 0, stream>>>(ei, T, log_b, msg);
    node_kernel<0><<<nodeBlocks, 256, 0, stream>>>(row, eid, msg, log_b0, log_b, out);

    // iterations 1..4
    for (int it = 1; it < 5; ++it) {
        edge_kernel<0><<<pairBlocks, 256, 0, stream>>>(ei, T, log_b, msg);
        if (it < 4)
            node_kernel<0><<<nodeBlocks, 256, 0, stream>>>(row, eid, msg, log_b0, log_b, out);
        else
            node_kernel<1><<<nodeBlocks, 256, 0, stream>>>(row, eid, msg, log_b0, log_b, out);
    }
}